// Round 17
// baseline (957.991 us; speedup 1.0000x reference)
//
#include <hip/hip_runtime.h>

#define WS_ALIGN(x) (((x) + 255) & ~(size_t)255)

typedef float f4v __attribute__((ext_vector_type(4)));
__device__ inline void nt_store4(float* p, float4 v) {
  __builtin_nontemporal_store(*(f4v*)&v, (f4v*)p);
}

// ---------------- degree: dst (CSR/norm) + src (CSC grouping), one pass ----------------
__global__ void k_count2(const int* __restrict__ src, const int* __restrict__ dst, int E,
                         int* __restrict__ deg_dst, int* __restrict__ deg_src) {
  int e = blockIdx.x * blockDim.x + threadIdx.x;
  if (e < E) {
    atomicAdd(&deg_dst[dst[e]], 1);
    atomicAdd(&deg_src[src[e]], 1);
  }
}

__global__ void k_dis(const int* __restrict__ deg, float* __restrict__ dis, int N) {
  int i = blockIdx.x * blockDim.x + threadIdx.x;
  if (i < N) dis[i] = rsqrtf((float)(deg[i] + 1));  // +1 self-loop
}

// ---------------- dual exclusive scan: block 0 -> dst arrays, block 1 -> src arrays ----------------
__global__ __launch_bounds__(1024) void k_scan2(const int* __restrict__ deg2,
                                                int* __restrict__ rowptr_d, int* __restrict__ cursor_d,
                                                int* __restrict__ rowptr_s, int* __restrict__ cursor_s,
                                                int N, int Etot) {
  const int* deg = deg2 + (size_t)blockIdx.x * N;
  int* rowptr = blockIdx.x ? rowptr_s : rowptr_d;
  int* cursor = blockIdx.x ? cursor_s : cursor_d;
  __shared__ int wsum[16];
  __shared__ int s_carry;
  int tid = threadIdx.x, lane = tid & 63, w = tid >> 6;
  if (tid == 0) { s_carry = 0; rowptr[N] = Etot; }
  __syncthreads();
  for (int base = 0; base < N; base += 4096) {
    int i0 = base + tid * 4;
    int v[4];
    #pragma unroll
    for (int u = 0; u < 4; ++u) {
      int i = i0 + u;
      v[u] = (i < N) ? deg[i] : 0;
    }
    int tsum = v[0] + v[1] + v[2] + v[3];
    int sc = tsum;
    #pragma unroll
    for (int off = 1; off < 64; off <<= 1) {
      int t = __shfl_up(sc, off);
      if (lane >= off) sc += t;
    }
    if (lane == 63) wsum[w] = sc;
    __syncthreads();
    if (w == 0 && lane < 16) {
      int xx = wsum[lane];
      #pragma unroll
      for (int off = 1; off < 16; off <<= 1) {
        int t = __shfl_up(xx, off);
        if (lane >= off) xx += t;
      }
      wsum[lane] = xx;
    }
    __syncthreads();
    int woff = (w == 0) ? 0 : wsum[w - 1];
    int excl = s_carry + woff + (sc - tsum);
    #pragma unroll
    for (int u = 0; u < 4; ++u) {
      int i = i0 + u;
      if (i < N) { rowptr[i] = excl; cursor[i] = excl; }
      excl += v[u];
    }
    __syncthreads();
    if (tid == 0) s_carry += wsum[15];
    __syncthreads();
  }
}

// ---------------- fill: dst-CSR (for agg) + src-grouped CSC (for decode) ----------------
__global__ void k_fill2(const int* __restrict__ src, const int* __restrict__ dst, int E,
                        int* __restrict__ cursor_d, unsigned short* __restrict__ csr16,
                        int* __restrict__ cursor_s, unsigned int* __restrict__ csc_pk,
                        unsigned int* __restrict__ csc_orig) {
  int e = blockIdx.x * blockDim.x + threadIdx.x;
  if (e < E) {
    int s = src[e];
    int d = dst[e];
    int pd = atomicAdd(&cursor_d[d], 1);
    csr16[pd] = (unsigned short)s;
    int ps = atomicAdd(&cursor_s[s], 1);
    csc_pk[ps] = (unsigned int)s | ((unsigned int)d << 16);
    csc_orig[ps] = (unsigned int)e;
  }
}

// ---------------- GEMM: writes C in SLICE-MAJOR: C[(col/16)*M + row][col%16] ----------------
#define BM 128
#define BN 128
#define BK 16
__global__ __launch_bounds__(256) void k_gemm_scale_sm(const float* __restrict__ A,
                                                       const float* __restrict__ B,
                                                       const float* __restrict__ dis,
                                                       float* __restrict__ C,
                                                       int M, int Nc, int K) {
  __shared__ float As[BK][BM];
  __shared__ float Bs[BK][BN];
  int tid = threadIdx.x;
  int block_row = blockIdx.x * BM;
  int block_col = blockIdx.y * BN;
  int tr = (tid >> 4) << 3;
  int tc = (tid & 15) << 3;
  float acc[8][8] = {};
  for (int k0 = 0; k0 < K; k0 += BK) {
    for (int t = tid; t < BM * BK / 4; t += 256) {
      int r = t >> 2;
      int cc = (t & 3) << 2;
      int gr = block_row + r;
      float4 v = {0.f, 0.f, 0.f, 0.f};
      if (gr < M) v = *(const float4*)(A + (size_t)gr * K + k0 + cc);
      As[cc + 0][r] = v.x; As[cc + 1][r] = v.y; As[cc + 2][r] = v.z; As[cc + 3][r] = v.w;
    }
    for (int t = tid; t < BK * BN / 4; t += 256) {
      int r = t >> 5;
      int cc = (t & 31) << 2;
      *(float4*)&Bs[r][cc] = *(const float4*)(B + (size_t)(k0 + r) * Nc + block_col + cc);
    }
    __syncthreads();
    #pragma unroll
    for (int k = 0; k < BK; ++k) {
      float a[8], b[8];
      *(float4*)&a[0] = *(const float4*)&As[k][tr];
      *(float4*)&a[4] = *(const float4*)&As[k][tr + 4];
      *(float4*)&b[0] = *(const float4*)&Bs[k][tc];
      *(float4*)&b[4] = *(const float4*)&Bs[k][tc + 4];
      #pragma unroll
      for (int i = 0; i < 8; ++i)
        #pragma unroll
        for (int j = 0; j < 8; ++j)
          acc[i][j] = fmaf(a[i], b[j], acc[i][j]);
    }
    __syncthreads();
  }
  int col0 = block_col + tc;                 // multiple of 8
  size_t base = ((size_t)(col0 >> 4) * M) * 16 + (col0 & 15);
  for (int i = 0; i < 8; ++i) {
    int gr = block_row + tr + i;
    if (gr >= M) break;
    float s = dis[gr];
    float4 v0 = {acc[i][0] * s, acc[i][1] * s, acc[i][2] * s, acc[i][3] * s};
    float4 v1 = {acc[i][4] * s, acc[i][5] * s, acc[i][6] * s, acc[i][7] * s};
    float* cp = C + base + (size_t)gr * 16;
    *(float4*)cp = v0;
    *(float4*)(cp + 4) = v1;
  }
}

// ---------------- XCD-pinned sliced aggregation (ONE phase per launch) — r16 proven ----------------
template <int FCH, bool OUTSLICE>
__global__ __launch_bounds__(256) void k_agg_xcd(const float* __restrict__ hs,
                                                 const int* __restrict__ rowptr,
                                                 const unsigned short* __restrict__ csr,
                                                 const float* __restrict__ dis,
                                                 const float* __restrict__ bias,
                                                 float* __restrict__ out,
                                                 int N, int do_relu, int phase) {
  int bid = blockIdx.x;
  int xcd = bid & 7;
  int wid = threadIdx.x >> 6;
  int lane = threadIdx.x & 63;
  int sub = lane >> 3;          // node within chunk (0..7)
  int epar = (lane >> 2) & 1;   // edge-parallel 0/1
  int c2 = lane & 3;            // float4 chunk of 16-ch row
  int wix = ((bid >> 3) << 2) + wid;           // wave index within XCD
  int wpx = ((int)(gridDim.x >> 3)) << 2;      // waves per XCD
  int nchunk = (N + 7) >> 3;

  int s = xcd + (phase << 3);
  const float* in = hs + (size_t)s * N * 16;
  for (int ch = wix; ch < nchunk; ch += wpx) {
    int node = (ch << 3) + sub;
    bool valid = node < N;
    int b0 = 0, e0 = 0;
    if (valid) { b0 = rowptr[node]; e0 = rowptr[node + 1]; }
    float4 acc = {0.f, 0.f, 0.f, 0.f};
    int j = b0 + epar;
    for (; j + 6 < e0; j += 8) {
      int i0 = csr[j];     int i1 = csr[j + 2];
      int i2 = csr[j + 4]; int i3 = csr[j + 6];
      float4 v0 = *(const float4*)(in + ((size_t)i0 << 4) + (c2 << 2));
      float4 v1 = *(const float4*)(in + ((size_t)i1 << 4) + (c2 << 2));
      float4 v2 = *(const float4*)(in + ((size_t)i2 << 4) + (c2 << 2));
      float4 v3 = *(const float4*)(in + ((size_t)i3 << 4) + (c2 << 2));
      acc.x += (v0.x + v1.x) + (v2.x + v3.x);
      acc.y += (v0.y + v1.y) + (v2.y + v3.y);
      acc.z += (v0.z + v1.z) + (v2.z + v3.z);
      acc.w += (v0.w + v1.w) + (v2.w + v3.w);
    }
    for (; j < e0; j += 2) {
      int idx = csr[j];
      float4 v = *(const float4*)(in + ((size_t)idx << 4) + (c2 << 2));
      acc.x += v.x; acc.y += v.y; acc.z += v.z; acc.w += v.w;
    }
    acc.x += __shfl_xor(acc.x, 4);
    acc.y += __shfl_xor(acc.y, 4);
    acc.z += __shfl_xor(acc.z, 4);
    acc.w += __shfl_xor(acc.w, 4);
    if (valid && epar == 0) {
      float4 self = *(const float4*)(in + ((size_t)node << 4) + (c2 << 2));
      float dn = dis[node];
      int col = (s << 4) + (c2 << 2);
      float4 bv = *(const float4*)(bias + col);
      float4 r;
      r.x = (acc.x + self.x) * dn + bv.x;
      r.y = (acc.y + self.y) * dn + bv.y;
      r.z = (acc.z + self.z) * dn + bv.z;
      r.w = (acc.w + self.w) * dn + bv.w;
      if (do_relu) {
        r.x = fmaxf(r.x, 0.f); r.y = fmaxf(r.y, 0.f);
        r.z = fmaxf(r.z, 0.f); r.w = fmaxf(r.w, 0.f);
      }
      if (OUTSLICE)
        nt_store4(out + (size_t)s * N * 16 + ((size_t)node << 4) + (c2 << 2), r);
      else
        nt_store4(out + (size_t)node * FCH + col, r);
    }
  }
}

// ---------------- XCD-pinned decode in CSC (src-grouped) order ----------------
// z : [8][N][16] slice-major. XCD x handles slice x for ALL positions.
// Positions are grouped by src (avg group 32): consecutive sub-lanes share
// the same za row -> L1 hits; only zb stays a random gather. Partial dots
// stored SEQUENTIALLY at partial[x*E + pos]; k_dreduce_g scatters to out.
__global__ __launch_bounds__(256) void k_decode_csc(const float* __restrict__ z,
                                                    const unsigned int* __restrict__ csc_pk,
                                                    float* __restrict__ partial,
                                                    int E, int N) {
  int bid = blockIdx.x;
  int xcd = bid & 7;
  int wid = threadIdx.x >> 6;
  int lane = threadIdx.x & 63;
  int c2 = lane & 3;
  int sub = lane >> 2;                          // 0..15
  int wix = ((bid >> 3) << 2) + wid;            // wave index within XCD
  int wpx = ((int)(gridDim.x >> 3)) << 2;       // waves per XCD
  const float* zc = z + (size_t)xcd * N * 16;
  float* pp = partial + (size_t)xcd * E;

  for (int e0 = wix * 64; e0 < E; e0 += wpx * 64) {
    float pv[4];
    int ev[4];
    #pragma unroll
    for (int q = 0; q < 4; ++q) {
      int e = e0 + q * 16 + sub;
      ev[q] = e;
      pv[q] = 0.f;
      if (e < E) {
        unsigned int pk = csc_pk[e];
        int a = (int)(pk & 0xFFFFu), d = (int)(pk >> 16);
        float4 za = *(const float4*)(zc + ((size_t)a << 4) + (c2 << 2));
        float4 zb = *(const float4*)(zc + ((size_t)d << 4) + (c2 << 2));
        pv[q] = za.x * zb.x + za.y * zb.y + za.z * zb.z + za.w * zb.w;
      }
    }
    #pragma unroll
    for (int q = 0; q < 4; ++q) {
      pv[q] += __shfl_xor(pv[q], 1);
      pv[q] += __shfl_xor(pv[q], 2);
    }
    if (c2 == 0) {
      #pragma unroll
      for (int q = 0; q < 4; ++q)
        if (ev[q] < E) pp[ev[q]] = pv[q];
    }
  }
}

// ---------------- dreduce: sum 8 slice-partials (sequential), scatter to out[orig] ----------------
__global__ void k_dreduce_g(const float* __restrict__ partial,
                            const unsigned int* __restrict__ orig,
                            float* __restrict__ out, int E) {
  int q = blockIdx.x * 256 + threadIdx.x;   // quad index
  int e = q << 2;
  if (e >= E) return;
  if (e + 4 <= E) {
    float4 s = *(const float4*)(partial + e);
    #pragma unroll
    for (int k = 1; k < 8; ++k) {
      float4 t = *(const float4*)(partial + (size_t)k * E + e);
      s.x += t.x; s.y += t.y; s.z += t.z; s.w += t.w;
    }
    uint4 o = *(const uint4*)(orig + e);
    out[o.x] = s.x; out[o.y] = s.y; out[o.z] = s.z; out[o.w] = s.w;
  } else {
    for (int i = e; i < E; ++i) {
      float s = 0.f;
      #pragma unroll
      for (int k = 0; k < 8; ++k) s += partial[(size_t)k * E + i];
      out[orig[i]] = s;
    }
  }
}

extern "C" void kernel_launch(void* const* d_in, const int* in_sizes, int n_in,
                              void* d_out, int out_size, void* d_ws, size_t ws_size,
                              hipStream_t stream) {
  const float* x  = (const float*)d_in[0];
  const int* eidx = (const int*)d_in[1];
  const float* W1 = (const float*)d_in[2];
  const float* b1 = (const float*)d_in[3];
  const float* W2 = (const float*)d_in[4];
  const float* b2 = (const float*)d_in[5];
  float* out = (float*)d_out;

  const int IN_CH = 256, HID = 256, OUT_CH = 128;
  const int N = in_sizes[0] / IN_CH;
  const int E = in_sizes[1] / 2;
  const int* esrc = eidx;
  const int* edst = eidx + E;

  char* p = (char*)d_ws;
  auto alloc = [&](size_t bytes) -> char* { char* r = p; p += WS_ALIGN(bytes); return r; };
  int*   deg2    = (int*)  alloc(sizeof(int) * 2 * N);   // [0,N): dst deg; [N,2N): src deg
  float* dis     = (float*)alloc(sizeof(float) * N);
  int*   rowptr  = (int*)  alloc(sizeof(int) * (N + 1));
  int*   cursor  = (int*)  alloc(sizeof(int) * N);
  int*   rowptr_s= (int*)  alloc(sizeof(int) * (N + 1));
  int*   cursor_s= (int*)  alloc(sizeof(int) * N);
  unsigned short* csr16   = (unsigned short*)alloc(sizeof(unsigned short) * (size_t)E);
  unsigned int*   csc_pk  = (unsigned int*) alloc(sizeof(unsigned int) * (size_t)E);
  unsigned int*   csc_orig= (unsigned int*) alloc(sizeof(unsigned int) * (size_t)E);
  float* bufA   = (float*)alloc(sizeof(float) * (size_t)N * HID);  // h1s / h2s; reused as decode partials
  float* bufB   = (float*)alloc(sizeof(float) * (size_t)N * HID);  // z1 (row-major) / z2 (slice-major)

  int* deg_dst = deg2;
  int* deg_src = deg2 + N;

  const int T = 256;
  hipMemsetAsync(deg2, 0, sizeof(int) * 2 * N, stream);
  hipLaunchKernelGGL(k_count2, dim3((E + T - 1) / T), dim3(T), 0, stream,
                     esrc, edst, E, deg_dst, deg_src);
  hipLaunchKernelGGL(k_dis, dim3((N + T - 1) / T), dim3(T), 0, stream, deg_dst, dis, N);
  hipLaunchKernelGGL(k_scan2, dim3(2), dim3(1024), 0, stream,
                     deg2, rowptr, cursor, rowptr_s, cursor_s, N, E);
  hipLaunchKernelGGL(k_fill2, dim3((E + T - 1) / T), dim3(T), 0, stream,
                     esrc, edst, E, cursor, csr16, cursor_s, csc_pk, csc_orig);

  const int PG = 2048;  // persistent grid: 8 blocks/CU, 256 blocks/XCD

  // conv1: h1s = (x @ W1)*dis[row] slice-major; z1 = relu(...) row-major
  dim3 g1((N + BM - 1) / BM, HID / BN);
  hipLaunchKernelGGL(k_gemm_scale_sm, g1, dim3(256), 0, stream, x, W1, dis, bufA, N, HID, IN_CH);
  hipLaunchKernelGGL((k_agg_xcd<256, false>), dim3(PG), dim3(256), 0, stream,
                     bufA, rowptr, csr16, dis, b1, bufB, N, 1, 0);
  hipLaunchKernelGGL((k_agg_xcd<256, false>), dim3(PG), dim3(256), 0, stream,
                     bufA, rowptr, csr16, dis, b1, bufB, N, 1, 1);

  // conv2: h2s = (z1 @ W2)*dis[row] slice-major; z2 slice-major
  dim3 g2((N + BM - 1) / BM, OUT_CH / BN);
  hipLaunchKernelGGL(k_gemm_scale_sm, g2, dim3(256), 0, stream, bufB, W2, dis, bufA, N, OUT_CH, HID);
  hipLaunchKernelGGL((k_agg_xcd<128, true>), dim3(PG), dim3(256), 0, stream,
                     bufA, rowptr, csr16, dis, b2, bufB, N, 0, 0);

  // decode in CSC order: per-XCD slice partials into bufA (h2s dead), then reduce+scatter
  hipLaunchKernelGGL(k_decode_csc, dim3(PG), dim3(256), 0, stream,
                     bufB, csc_pk, bufA, E, N);
  hipLaunchKernelGGL(k_dreduce_g, dim3((E / 4 + 255) / 256), dim3(256), 0, stream,
                     bufA, csc_orig, out, E);
}

// Round 18
// 711.622 us; speedup vs baseline: 1.3462x; 1.3462x over previous
//
#include <hip/hip_runtime.h>

#define WS_ALIGN(x) (((x) + 255) & ~(size_t)255)

typedef float f4v __attribute__((ext_vector_type(4)));
__device__ inline void nt_store4(float* p, float4 v) {
  __builtin_nontemporal_store(*(f4v*)&v, (f4v*)p);
}

// ---------------- pack edges (N < 65536) + dst-degree count, one coalesced pass ----------------
__global__ void k_pack_count(const int* __restrict__ src, const int* __restrict__ dst, int E,
                             unsigned int* __restrict__ packed, int* __restrict__ deg) {
  int e = blockIdx.x * blockDim.x + threadIdx.x;
  if (e < E) {
    int s = src[e];
    int d = dst[e];
    packed[e] = (unsigned int)s | ((unsigned int)d << 16);
    atomicAdd(&deg[d], 1);
  }
}

__global__ void k_dis(const int* __restrict__ deg, float* __restrict__ dis, int N) {
  int i = blockIdx.x * blockDim.x + threadIdx.x;
  if (i < N) dis[i] = rsqrtf((float)(deg[i] + 1));  // +1 self-loop
}

// ---------------- exclusive scan (single block) ----------------
__global__ __launch_bounds__(1024) void k_scan(const int* __restrict__ deg,
                                               int* __restrict__ rowptr,
                                               int* __restrict__ cursor,
                                               int N, int Etot) {
  __shared__ int wsum[16];
  __shared__ int s_carry;
  int tid = threadIdx.x, lane = tid & 63, w = tid >> 6;
  if (tid == 0) { s_carry = 0; rowptr[N] = Etot; }
  __syncthreads();
  for (int base = 0; base < N; base += 4096) {
    int i0 = base + tid * 4;
    int v[4];
    #pragma unroll
    for (int u = 0; u < 4; ++u) {
      int i = i0 + u;
      v[u] = (i < N) ? deg[i] : 0;
    }
    int tsum = v[0] + v[1] + v[2] + v[3];
    int sc = tsum;
    #pragma unroll
    for (int off = 1; off < 64; off <<= 1) {
      int t = __shfl_up(sc, off);
      if (lane >= off) sc += t;
    }
    if (lane == 63) wsum[w] = sc;
    __syncthreads();
    if (w == 0 && lane < 16) {
      int xx = wsum[lane];
      #pragma unroll
      for (int off = 1; off < 16; off <<= 1) {
        int t = __shfl_up(xx, off);
        if (lane >= off) xx += t;
      }
      wsum[lane] = xx;
    }
    __syncthreads();
    int woff = (w == 0) ? 0 : wsum[w - 1];
    int excl = s_carry + woff + (sc - tsum);
    #pragma unroll
    for (int u = 0; u < 4; ++u) {
      int i = i0 + u;
      if (i < N) { rowptr[i] = excl; cursor[i] = excl; }
      excl += v[u];
    }
    __syncthreads();
    if (tid == 0) s_carry += wsum[15];
    __syncthreads();
  }
}

// ---------------- XCD-partitioned CSR fill ----------------
// Each XCD grid-strides over ALL packed edges but commits only dst in its
// N/8 range: its cursor segment (25KB) and csr16 segment (~0.4MB) stay
// resident in its own L2 -> no cross-XCD atomic ping-pong, no write-allocate
// round-trips to HBM. Tax: 8x redundant packed reads (51MB, L3-served).
__global__ __launch_bounds__(256) void k_fill_xcd(const unsigned int* __restrict__ packed,
                                                  int E, int N,
                                                  int* __restrict__ cursor,
                                                  unsigned short* __restrict__ csr16) {
  int bid = blockIdx.x;
  int xcd = bid & 7;
  int tix = ((bid >> 3) << 8) + threadIdx.x;      // thread index within XCD
  int tpx = ((int)(gridDim.x >> 3)) << 8;         // threads per XCD
  int lo = (int)(((long long)N * xcd) >> 3);
  int hi = (int)(((long long)N * (xcd + 1)) >> 3);
  for (int e = tix; e < E; e += tpx) {
    unsigned int pk = packed[e];
    int d = (int)(pk >> 16);
    if (d >= lo && d < hi) {
      int pos = atomicAdd(&cursor[d], 1);
      csr16[pos] = (unsigned short)(pk & 0xFFFFu);
    }
  }
}

// ---------------- GEMM: writes C in SLICE-MAJOR: C[(col/16)*M + row][col%16] ----------------
#define BM 128
#define BN 128
#define BK 16
__global__ __launch_bounds__(256) void k_gemm_scale_sm(const float* __restrict__ A,
                                                       const float* __restrict__ B,
                                                       const float* __restrict__ dis,
                                                       float* __restrict__ C,
                                                       int M, int Nc, int K) {
  __shared__ float As[BK][BM];
  __shared__ float Bs[BK][BN];
  int tid = threadIdx.x;
  int block_row = blockIdx.x * BM;
  int block_col = blockIdx.y * BN;
  int tr = (tid >> 4) << 3;
  int tc = (tid & 15) << 3;
  float acc[8][8] = {};
  for (int k0 = 0; k0 < K; k0 += BK) {
    for (int t = tid; t < BM * BK / 4; t += 256) {
      int r = t >> 2;
      int cc = (t & 3) << 2;
      int gr = block_row + r;
      float4 v = {0.f, 0.f, 0.f, 0.f};
      if (gr < M) v = *(const float4*)(A + (size_t)gr * K + k0 + cc);
      As[cc + 0][r] = v.x; As[cc + 1][r] = v.y; As[cc + 2][r] = v.z; As[cc + 3][r] = v.w;
    }
    for (int t = tid; t < BK * BN / 4; t += 256) {
      int r = t >> 5;
      int cc = (t & 31) << 2;
      *(float4*)&Bs[r][cc] = *(const float4*)(B + (size_t)(k0 + r) * Nc + block_col + cc);
    }
    __syncthreads();
    #pragma unroll
    for (int k = 0; k < BK; ++k) {
      float a[8], b[8];
      *(float4*)&a[0] = *(const float4*)&As[k][tr];
      *(float4*)&a[4] = *(const float4*)&As[k][tr + 4];
      *(float4*)&b[0] = *(const float4*)&Bs[k][tc];
      *(float4*)&b[4] = *(const float4*)&Bs[k][tc + 4];
      #pragma unroll
      for (int i = 0; i < 8; ++i)
        #pragma unroll
        for (int j = 0; j < 8; ++j)
          acc[i][j] = fmaf(a[i], b[j], acc[i][j]);
    }
    __syncthreads();
  }
  int col0 = block_col + tc;                 // multiple of 8
  size_t base = ((size_t)(col0 >> 4) * M) * 16 + (col0 & 15);
  for (int i = 0; i < 8; ++i) {
    int gr = block_row + tr + i;
    if (gr >= M) break;
    float s = dis[gr];
    float4 v0 = {acc[i][0] * s, acc[i][1] * s, acc[i][2] * s, acc[i][3] * s};
    float4 v1 = {acc[i][4] * s, acc[i][5] * s, acc[i][6] * s, acc[i][7] * s};
    float* cp = C + base + (size_t)gr * 16;
    *(float4*)cp = v0;
    *(float4*)(cp + 4) = v1;
  }
}

// ---------------- XCD-pinned sliced aggregation (ONE phase per launch) — r16 proven ----------------
template <int FCH, bool OUTSLICE>
__global__ __launch_bounds__(256) void k_agg_xcd(const float* __restrict__ hs,
                                                 const int* __restrict__ rowptr,
                                                 const unsigned short* __restrict__ csr,
                                                 const float* __restrict__ dis,
                                                 const float* __restrict__ bias,
                                                 float* __restrict__ out,
                                                 int N, int do_relu, int phase) {
  int bid = blockIdx.x;
  int xcd = bid & 7;
  int wid = threadIdx.x >> 6;
  int lane = threadIdx.x & 63;
  int sub = lane >> 3;          // node within chunk (0..7)
  int epar = (lane >> 2) & 1;   // edge-parallel 0/1
  int c2 = lane & 3;            // float4 chunk of 16-ch row
  int wix = ((bid >> 3) << 2) + wid;           // wave index within XCD
  int wpx = ((int)(gridDim.x >> 3)) << 2;      // waves per XCD
  int nchunk = (N + 7) >> 3;

  int s = xcd + (phase << 3);
  const float* in = hs + (size_t)s * N * 16;
  for (int ch = wix; ch < nchunk; ch += wpx) {
    int node = (ch << 3) + sub;
    bool valid = node < N;
    int b0 = 0, e0 = 0;
    if (valid) { b0 = rowptr[node]; e0 = rowptr[node + 1]; }
    float4 acc = {0.f, 0.f, 0.f, 0.f};
    int j = b0 + epar;
    for (; j + 6 < e0; j += 8) {
      int i0 = csr[j];     int i1 = csr[j + 2];
      int i2 = csr[j + 4]; int i3 = csr[j + 6];
      float4 v0 = *(const float4*)(in + ((size_t)i0 << 4) + (c2 << 2));
      float4 v1 = *(const float4*)(in + ((size_t)i1 << 4) + (c2 << 2));
      float4 v2 = *(const float4*)(in + ((size_t)i2 << 4) + (c2 << 2));
      float4 v3 = *(const float4*)(in + ((size_t)i3 << 4) + (c2 << 2));
      acc.x += (v0.x + v1.x) + (v2.x + v3.x);
      acc.y += (v0.y + v1.y) + (v2.y + v3.y);
      acc.z += (v0.z + v1.z) + (v2.z + v3.z);
      acc.w += (v0.w + v1.w) + (v2.w + v3.w);
    }
    for (; j < e0; j += 2) {
      int idx = csr[j];
      float4 v = *(const float4*)(in + ((size_t)idx << 4) + (c2 << 2));
      acc.x += v.x; acc.y += v.y; acc.z += v.z; acc.w += v.w;
    }
    acc.x += __shfl_xor(acc.x, 4);
    acc.y += __shfl_xor(acc.y, 4);
    acc.z += __shfl_xor(acc.z, 4);
    acc.w += __shfl_xor(acc.w, 4);
    if (valid && epar == 0) {
      float4 self = *(const float4*)(in + ((size_t)node << 4) + (c2 << 2));
      float dn = dis[node];
      int col = (s << 4) + (c2 << 2);
      float4 bv = *(const float4*)(bias + col);
      float4 r;
      r.x = (acc.x + self.x) * dn + bv.x;
      r.y = (acc.y + self.y) * dn + bv.y;
      r.z = (acc.z + self.z) * dn + bv.z;
      r.w = (acc.w + self.w) * dn + bv.w;
      if (do_relu) {
        r.x = fmaxf(r.x, 0.f); r.y = fmaxf(r.y, 0.f);
        r.z = fmaxf(r.z, 0.f); r.w = fmaxf(r.w, 0.f);
      }
      if (OUTSLICE)
        nt_store4(out + (size_t)s * N * 16 + ((size_t)node << 4) + (c2 << 2), r);
      else
        nt_store4(out + (size_t)node * FCH + col, r);
    }
  }
}

// ---------------- XCD-pinned decode, coalesced 4-lane rows, 64 edges/wave-iter ----------------
__global__ __launch_bounds__(256) void k_decode_xcd4(const float* __restrict__ z,
                                                     const unsigned int* __restrict__ packed,
                                                     float* __restrict__ partial,
                                                     int E, int N) {
  int bid = blockIdx.x;
  int xcd = bid & 7;
  int wid = threadIdx.x >> 6;
  int lane = threadIdx.x & 63;
  int c2 = lane & 3;
  int sub = lane >> 2;                          // 0..15
  int wix = ((bid >> 3) << 2) + wid;            // wave index within XCD
  int wpx = ((int)(gridDim.x >> 3)) << 2;       // waves per XCD
  const float* zc = z + (size_t)xcd * N * 16;
  float* pp = partial + (size_t)xcd * E;

  for (int e0 = wix * 64; e0 < E; e0 += wpx * 64) {
    float pv[4];
    int ev[4];
    #pragma unroll
    for (int q = 0; q < 4; ++q) {
      int e = e0 + q * 16 + sub;
      ev[q] = e;
      pv[q] = 0.f;
      if (e < E) {
        unsigned int pk = packed[e];
        int a = (int)(pk & 0xFFFFu), d = (int)(pk >> 16);
        float4 za = *(const float4*)(zc + ((size_t)a << 4) + (c2 << 2));
        float4 zb = *(const float4*)(zc + ((size_t)d << 4) + (c2 << 2));
        pv[q] = za.x * zb.x + za.y * zb.y + za.z * zb.z + za.w * zb.w;
      }
    }
    #pragma unroll
    for (int q = 0; q < 4; ++q) {
      pv[q] += __shfl_xor(pv[q], 1);
      pv[q] += __shfl_xor(pv[q], 2);
    }
    if (c2 == 0) {
      #pragma unroll
      for (int q = 0; q < 4; ++q)
        if (ev[q] < E) pp[ev[q]] = pv[q];
    }
  }
}

// ---------------- dreduce: float4 over edges ----------------
__global__ void k_dreduce4(const float* __restrict__ partial, float* __restrict__ out, int E) {
  int q = blockIdx.x * 256 + threadIdx.x;   // quad index
  int e = q << 2;
  if (e >= E) return;
  if (e + 4 <= E) {
    float4 s = *(const float4*)(partial + e);
    #pragma unroll
    for (int k = 1; k < 8; ++k) {
      float4 t = *(const float4*)(partial + (size_t)k * E + e);
      s.x += t.x; s.y += t.y; s.z += t.z; s.w += t.w;
    }
    *(float4*)(out + e) = s;
  } else {
    for (int i = e; i < E; ++i) {
      float s = 0.f;
      #pragma unroll
      for (int k = 0; k < 8; ++k) s += partial[(size_t)k * E + i];
      out[i] = s;
    }
  }
}

extern "C" void kernel_launch(void* const* d_in, const int* in_sizes, int n_in,
                              void* d_out, int out_size, void* d_ws, size_t ws_size,
                              hipStream_t stream) {
  const float* x  = (const float*)d_in[0];
  const int* eidx = (const int*)d_in[1];
  const float* W1 = (const float*)d_in[2];
  const float* b1 = (const float*)d_in[3];
  const float* W2 = (const float*)d_in[4];
  const float* b2 = (const float*)d_in[5];
  float* out = (float*)d_out;

  const int IN_CH = 256, HID = 256, OUT_CH = 128;
  const int N = in_sizes[0] / IN_CH;
  const int E = in_sizes[1] / 2;
  const int* esrc = eidx;
  const int* edst = eidx + E;

  char* p = (char*)d_ws;
  auto alloc = [&](size_t bytes) -> char* { char* r = p; p += WS_ALIGN(bytes); return r; };
  int*   deg    = (int*)  alloc(sizeof(int) * N);
  float* dis    = (float*)alloc(sizeof(float) * N);
  int*   rowptr = (int*)  alloc(sizeof(int) * (N + 1));
  int*   cursor = (int*)  alloc(sizeof(int) * N);
  unsigned short* csr16 = (unsigned short*)alloc(sizeof(unsigned short) * (size_t)E);
  unsigned int*   packed = (unsigned int*) alloc(sizeof(unsigned int) * (size_t)E);
  float* bufA   = (float*)alloc(sizeof(float) * (size_t)N * HID);  // h1s / h2s; reused as decode partials
  float* bufB   = (float*)alloc(sizeof(float) * (size_t)N * HID);  // z1 (row-major) / z2 (slice-major)

  const int T = 256;
  const int PG = 2048;  // persistent grid: 8 blocks/CU, 256 blocks/XCD

  hipMemsetAsync(deg, 0, sizeof(int) * N, stream);
  hipLaunchKernelGGL(k_pack_count, dim3((E + T - 1) / T), dim3(T), 0, stream,
                     esrc, edst, E, packed, deg);
  hipLaunchKernelGGL(k_dis, dim3((N + T - 1) / T), dim3(T), 0, stream, deg, dis, N);
  hipLaunchKernelGGL(k_scan, dim3(1), dim3(1024), 0, stream, deg, rowptr, cursor, N, E);
  hipLaunchKernelGGL(k_fill_xcd, dim3(PG), dim3(T), 0, stream, packed, E, N, cursor, csr16);

  // conv1: h1s = (x @ W1)*dis[row] slice-major; z1 = relu(...) row-major
  dim3 g1((N + BM - 1) / BM, HID / BN);
  hipLaunchKernelGGL(k_gemm_scale_sm, g1, dim3(256), 0, stream, x, W1, dis, bufA, N, HID, IN_CH);
  hipLaunchKernelGGL((k_agg_xcd<256, false>), dim3(PG), dim3(256), 0, stream,
                     bufA, rowptr, csr16, dis, b1, bufB, N, 1, 0);
  hipLaunchKernelGGL((k_agg_xcd<256, false>), dim3(PG), dim3(256), 0, stream,
                     bufA, rowptr, csr16, dis, b1, bufB, N, 1, 1);

  // conv2: h2s = (z1 @ W2)*dis[row] slice-major; z2 slice-major
  dim3 g2((N + BM - 1) / BM, OUT_CH / BN);
  hipLaunchKernelGGL(k_gemm_scale_sm, g2, dim3(256), 0, stream, bufB, W2, dis, bufA, N, OUT_CH, HID);
  hipLaunchKernelGGL((k_agg_xcd<128, true>), dim3(PG), dim3(256), 0, stream,
                     bufA, rowptr, csr16, dis, b2, bufB, N, 0, 0);

  // decode: per-XCD slice partial dots into bufA (h2s dead), then reduce
  hipLaunchKernelGGL(k_decode_xcd4, dim3(PG), dim3(256), 0, stream,
                     bufB, packed, bufA, E, N);
  hipLaunchKernelGGL(k_dreduce4, dim3((E / 4 + 255) / 256), dim3(256), 0, stream,
                     bufA, out, E);
}

// Round 19
// 627.280 us; speedup vs baseline: 1.5272x; 1.1345x over previous
//
#include <hip/hip_runtime.h>

#define WS_ALIGN(x) (((x) + 255) & ~(size_t)255)

typedef float f4v __attribute__((ext_vector_type(4)));
typedef __attribute__((ext_vector_type(8))) short bf16x8;
typedef __attribute__((ext_vector_type(4))) float f32x4;
typedef __attribute__((ext_vector_type(4))) unsigned short us4;

__device__ inline void nt_store4(float* p, float4 v) {
  __builtin_nontemporal_store(*(f4v*)&v, (f4v*)p);
}

__device__ inline unsigned short f2bf(float v) {
  unsigned int u = __float_as_uint(v);
  u += 0x7FFF + ((u >> 16) & 1);   // RNE
  return (unsigned short)(u >> 16);
}
__device__ inline float bf2f(unsigned short h) {
  return __uint_as_float(((unsigned int)h) << 16);
}

// ---------------- pack edges (N < 65536) + dst-degree count, one coalesced pass ----------------
__global__ void k_pack_count(const int* __restrict__ src, const int* __restrict__ dst, int E,
                             unsigned int* __restrict__ packed, int* __restrict__ deg) {
  int e = blockIdx.x * blockDim.x + threadIdx.x;
  if (e < E) {
    int s = src[e];
    int d = dst[e];
    packed[e] = (unsigned int)s | ((unsigned int)d << 16);
    atomicAdd(&deg[d], 1);
  }
}

__global__ void k_dis(const int* __restrict__ deg, float* __restrict__ dis, int N) {
  int i = blockIdx.x * blockDim.x + threadIdx.x;
  if (i < N) dis[i] = rsqrtf((float)(deg[i] + 1));  // +1 self-loop
}

// ---------------- exclusive scan (single block) ----------------
__global__ __launch_bounds__(1024) void k_scan(const int* __restrict__ deg,
                                               int* __restrict__ rowptr,
                                               int* __restrict__ cursor,
                                               int N, int Etot) {
  __shared__ int wsum[16];
  __shared__ int s_carry;
  int tid = threadIdx.x, lane = tid & 63, w = tid >> 6;
  if (tid == 0) { s_carry = 0; rowptr[N] = Etot; }
  __syncthreads();
  for (int base = 0; base < N; base += 4096) {
    int i0 = base + tid * 4;
    int v[4];
    #pragma unroll
    for (int u = 0; u < 4; ++u) {
      int i = i0 + u;
      v[u] = (i < N) ? deg[i] : 0;
    }
    int tsum = v[0] + v[1] + v[2] + v[3];
    int sc = tsum;
    #pragma unroll
    for (int off = 1; off < 64; off <<= 1) {
      int t = __shfl_up(sc, off);
      if (lane >= off) sc += t;
    }
    if (lane == 63) wsum[w] = sc;
    __syncthreads();
    if (w == 0 && lane < 16) {
      int xx = wsum[lane];
      #pragma unroll
      for (int off = 1; off < 16; off <<= 1) {
        int t = __shfl_up(xx, off);
        if (lane >= off) xx += t;
      }
      wsum[lane] = xx;
    }
    __syncthreads();
    int woff = (w == 0) ? 0 : wsum[w - 1];
    int excl = s_carry + woff + (sc - tsum);
    #pragma unroll
    for (int u = 0; u < 4; ++u) {
      int i = i0 + u;
      if (i < N) { rowptr[i] = excl; cursor[i] = excl; }
      excl += v[u];
    }
    __syncthreads();
    if (tid == 0) s_carry += wsum[15];
    __syncthreads();
  }
}

// ---------------- XCD-partitioned CSR fill (r18 proven) ----------------
__global__ __launch_bounds__(256) void k_fill_xcd(const unsigned int* __restrict__ packed,
                                                  int E, int N,
                                                  int* __restrict__ cursor,
                                                  unsigned short* __restrict__ csr16) {
  int bid = blockIdx.x;
  int xcd = bid & 7;
  int tix = ((bid >> 3) << 8) + threadIdx.x;
  int tpx = ((int)(gridDim.x >> 3)) << 8;
  int lo = (int)(((long long)N * xcd) >> 3);
  int hi = (int)(((long long)N * (xcd + 1)) >> 3);
  for (int e = tix; e < E; e += tpx) {
    unsigned int pk = packed[e];
    int d = (int)(pk >> 16);
    if (d >= lo && d < hi) {
      int pos = atomicAdd(&cursor[d], 1);
      csr16[pos] = (unsigned short)(pk & 0xFFFFu);
    }
  }
}

// ---------------- split-bf16 MFMA GEMM, slice-major output ----------------
// C[m][n] = (sum_k A[m][k]*B[k][n]) * dis[m], written C[(n/16)*M + m][n%16].
// A,B fp32; split a = ah + al (two-level bf16); D = Ah*Bh + Ah*Bl + Al*Bh
// (dropped Al*Bl ~ 2^-18 relative). mfma_f32_16x16x32_bf16, fp32 accum.
// Tile 128x64, BK=32, 4 waves; wave w: rows [w*32,w*32+32), 2x4 fragments.
// A staged [row][k] hi/lo bf16, B staged TRANSPOSED [col][k] hi/lo;
// rows padded to 40 bf16 (80B: 16B-aligned b128 reads, <=2-way banks).
#define APAD 40
__global__ __launch_bounds__(256) void k_gemm_mfma_sm(const float* __restrict__ A,
                                                      const float* __restrict__ B,
                                                      const float* __restrict__ dis,
                                                      float* __restrict__ C,
                                                      int M, int Nc, int K) {
  __shared__ unsigned short As_hi[128][APAD];
  __shared__ unsigned short As_lo[128][APAD];
  __shared__ unsigned short Bs_hi[64][APAD];
  __shared__ unsigned short Bs_lo[64][APAD];
  int tid = threadIdx.x;
  int wv = tid >> 6, lane = tid & 63;
  int block_row = blockIdx.x * 128;
  int block_col = blockIdx.y * 64;

  f32x4 acc[2][4] = {};

  for (int k0 = 0; k0 < K; k0 += 32) {
    // stage A: 128 rows x 32 k; thread t -> row t>>1, half (t&1)
    {
      int row = tid >> 1;
      int grow = block_row + row;
      int qb = (tid & 1) * 16;  // float offset in row
      const float* ap = A + (size_t)grow * K + k0 + qb;
      #pragma unroll
      for (int i = 0; i < 4; ++i) {
        float4 v = {0.f, 0.f, 0.f, 0.f};
        if (grow < M) v = *(const float4*)(ap + i * 4);
        us4 h, l;
        h.x = f2bf(v.x); h.y = f2bf(v.y); h.z = f2bf(v.z); h.w = f2bf(v.w);
        l.x = f2bf(v.x - bf2f(h.x)); l.y = f2bf(v.y - bf2f(h.y));
        l.z = f2bf(v.z - bf2f(h.z)); l.w = f2bf(v.w - bf2f(h.w));
        *(us4*)&As_hi[row][qb + i * 4] = h;
        *(us4*)&As_lo[row][qb + i * 4] = l;
      }
    }
    // stage B transposed: thread t -> col t&63, k-slab (t>>6)*8
    {
      int n = tid & 63;
      int ksb = (tid >> 6) * 8;
      int gn = block_col + n;
      #pragma unroll
      for (int j = 0; j < 8; ++j) {
        float v = B[(size_t)(k0 + ksb + j) * Nc + gn];
        unsigned short h = f2bf(v);
        Bs_hi[n][ksb + j] = h;
        Bs_lo[n][ksb + j] = f2bf(v - bf2f(h));
      }
    }
    __syncthreads();
    int frow = lane & 15;
    int fk = (lane >> 4) * 8;
    bf16x8 ah[2], al[2], bh[4], bl[4];
    #pragma unroll
    for (int rf = 0; rf < 2; ++rf) {
      int r = wv * 32 + rf * 16 + frow;
      ah[rf] = *(const bf16x8*)&As_hi[r][fk];
      al[rf] = *(const bf16x8*)&As_lo[r][fk];
    }
    #pragma unroll
    for (int cf = 0; cf < 4; ++cf) {
      int c = cf * 16 + frow;
      bh[cf] = *(const bf16x8*)&Bs_hi[c][fk];
      bl[cf] = *(const bf16x8*)&Bs_lo[c][fk];
    }
    #pragma unroll
    for (int rf = 0; rf < 2; ++rf)
      #pragma unroll
      for (int cf = 0; cf < 4; ++cf) {
        acc[rf][cf] = __builtin_amdgcn_mfma_f32_16x16x32_bf16(ah[rf], bh[cf], acc[rf][cf], 0, 0, 0);
        acc[rf][cf] = __builtin_amdgcn_mfma_f32_16x16x32_bf16(ah[rf], bl[cf], acc[rf][cf], 0, 0, 0);
        acc[rf][cf] = __builtin_amdgcn_mfma_f32_16x16x32_bf16(al[rf], bh[cf], acc[rf][cf], 0, 0, 0);
      }
    __syncthreads();
  }
  // epilogue: D layout col=lane&15, row=(lane>>4)*4+reg (verified m89/m91)
  int fcol = lane & 15;
  #pragma unroll
  for (int rf = 0; rf < 2; ++rf) {
    int rbase = block_row + wv * 32 + rf * 16 + (lane >> 4) * 4;
    #pragma unroll
    for (int j = 0; j < 4; ++j) {
      int row = rbase + j;
      if (row < M) {
        float dn = dis[row];
        #pragma unroll
        for (int cf = 0; cf < 4; ++cf) {
          int sl = (block_col >> 4) + cf;
          C[((size_t)sl * M + row) * 16 + fcol] = acc[rf][cf][j] * dn;
        }
      }
    }
  }
}

// ---------------- XCD-pinned sliced aggregation (ONE phase per launch) — r16 proven ----------------
template <int FCH, bool OUTSLICE>
__global__ __launch_bounds__(256) void k_agg_xcd(const float* __restrict__ hs,
                                                 const int* __restrict__ rowptr,
                                                 const unsigned short* __restrict__ csr,
                                                 const float* __restrict__ dis,
                                                 const float* __restrict__ bias,
                                                 float* __restrict__ out,
                                                 int N, int do_relu, int phase) {
  int bid = blockIdx.x;
  int xcd = bid & 7;
  int wid = threadIdx.x >> 6;
  int lane = threadIdx.x & 63;
  int sub = lane >> 3;          // node within chunk (0..7)
  int epar = (lane >> 2) & 1;   // edge-parallel 0/1
  int c2 = lane & 3;            // float4 chunk of 16-ch row
  int wix = ((bid >> 3) << 2) + wid;
  int wpx = ((int)(gridDim.x >> 3)) << 2;
  int nchunk = (N + 7) >> 3;

  int s = xcd + (phase << 3);
  const float* in = hs + (size_t)s * N * 16;
  for (int ch = wix; ch < nchunk; ch += wpx) {
    int node = (ch << 3) + sub;
    bool valid = node < N;
    int b0 = 0, e0 = 0;
    if (valid) { b0 = rowptr[node]; e0 = rowptr[node + 1]; }
    float4 acc = {0.f, 0.f, 0.f, 0.f};
    int j = b0 + epar;
    for (; j + 6 < e0; j += 8) {
      int i0 = csr[j];     int i1 = csr[j + 2];
      int i2 = csr[j + 4]; int i3 = csr[j + 6];
      float4 v0 = *(const float4*)(in + ((size_t)i0 << 4) + (c2 << 2));
      float4 v1 = *(const float4*)(in + ((size_t)i1 << 4) + (c2 << 2));
      float4 v2 = *(const float4*)(in + ((size_t)i2 << 4) + (c2 << 2));
      float4 v3 = *(const float4*)(in + ((size_t)i3 << 4) + (c2 << 2));
      acc.x += (v0.x + v1.x) + (v2.x + v3.x);
      acc.y += (v0.y + v1.y) + (v2.y + v3.y);
      acc.z += (v0.z + v1.z) + (v2.z + v3.z);
      acc.w += (v0.w + v1.w) + (v2.w + v3.w);
    }
    for (; j < e0; j += 2) {
      int idx = csr[j];
      float4 v = *(const float4*)(in + ((size_t)idx << 4) + (c2 << 2));
      acc.x += v.x; acc.y += v.y; acc.z += v.z; acc.w += v.w;
    }
    acc.x += __shfl_xor(acc.x, 4);
    acc.y += __shfl_xor(acc.y, 4);
    acc.z += __shfl_xor(acc.z, 4);
    acc.w += __shfl_xor(acc.w, 4);
    if (valid && epar == 0) {
      float4 self = *(const float4*)(in + ((size_t)node << 4) + (c2 << 2));
      float dn = dis[node];
      int col = (s << 4) + (c2 << 2);
      float4 bv = *(const float4*)(bias + col);
      float4 r;
      r.x = (acc.x + self.x) * dn + bv.x;
      r.y = (acc.y + self.y) * dn + bv.y;
      r.z = (acc.z + self.z) * dn + bv.z;
      r.w = (acc.w + self.w) * dn + bv.w;
      if (do_relu) {
        r.x = fmaxf(r.x, 0.f); r.y = fmaxf(r.y, 0.f);
        r.z = fmaxf(r.z, 0.f); r.w = fmaxf(r.w, 0.f);
      }
      if (OUTSLICE)
        nt_store4(out + (size_t)s * N * 16 + ((size_t)node << 4) + (c2 << 2), r);
      else
        nt_store4(out + (size_t)node * FCH + col, r);
    }
  }
}

// ---------------- XCD-pinned decode, coalesced 4-lane rows, 64 edges/wave-iter ----------------
__global__ __launch_bounds__(256) void k_decode_xcd4(const float* __restrict__ z,
                                                     const unsigned int* __restrict__ packed,
                                                     float* __restrict__ partial,
                                                     int E, int N) {
  int bid = blockIdx.x;
  int xcd = bid & 7;
  int wid = threadIdx.x >> 6;
  int lane = threadIdx.x & 63;
  int c2 = lane & 3;
  int sub = lane >> 2;
  int wix = ((bid >> 3) << 2) + wid;
  int wpx = ((int)(gridDim.x >> 3)) << 2;
  const float* zc = z + (size_t)xcd * N * 16;
  float* pp = partial + (size_t)xcd * E;

  for (int e0 = wix * 64; e0 < E; e0 += wpx * 64) {
    float pv[4];
    int ev[4];
    #pragma unroll
    for (int q = 0; q < 4; ++q) {
      int e = e0 + q * 16 + sub;
      ev[q] = e;
      pv[q] = 0.f;
      if (e < E) {
        unsigned int pk = packed[e];
        int a = (int)(pk & 0xFFFFu), d = (int)(pk >> 16);
        float4 za = *(const float4*)(zc + ((size_t)a << 4) + (c2 << 2));
        float4 zb = *(const float4*)(zc + ((size_t)d << 4) + (c2 << 2));
        pv[q] = za.x * zb.x + za.y * zb.y + za.z * zb.z + za.w * zb.w;
      }
    }
    #pragma unroll
    for (int q = 0; q < 4; ++q) {
      pv[q] += __shfl_xor(pv[q], 1);
      pv[q] += __shfl_xor(pv[q], 2);
    }
    if (c2 == 0) {
      #pragma unroll
      for (int q = 0; q < 4; ++q)
        if (ev[q] < E) pp[ev[q]] = pv[q];
    }
  }
}

// ---------------- dreduce: float4 over edges ----------------
__global__ void k_dreduce4(const float* __restrict__ partial, float* __restrict__ out, int E) {
  int q = blockIdx.x * 256 + threadIdx.x;
  int e = q << 2;
  if (e >= E) return;
  if (e + 4 <= E) {
    float4 s = *(const float4*)(partial + e);
    #pragma unroll
    for (int k = 1; k < 8; ++k) {
      float4 t = *(const float4*)(partial + (size_t)k * E + e);
      s.x += t.x; s.y += t.y; s.z += t.z; s.w += t.w;
    }
    *(float4*)(out + e) = s;
  } else {
    for (int i = e; i < E; ++i) {
      float s = 0.f;
      #pragma unroll
      for (int k = 0; k < 8; ++k) s += partial[(size_t)k * E + i];
      out[i] = s;
    }
  }
}

extern "C" void kernel_launch(void* const* d_in, const int* in_sizes, int n_in,
                              void* d_out, int out_size, void* d_ws, size_t ws_size,
                              hipStream_t stream) {
  const float* x  = (const float*)d_in[0];
  const int* eidx = (const int*)d_in[1];
  const float* W1 = (const float*)d_in[2];
  const float* b1 = (const float*)d_in[3];
  const float* W2 = (const float*)d_in[4];
  const float* b2 = (const float*)d_in[5];
  float* out = (float*)d_out;

  const int IN_CH = 256, HID = 256, OUT_CH = 128;
  const int N = in_sizes[0] / IN_CH;
  const int E = in_sizes[1] / 2;
  const int* esrc = eidx;
  const int* edst = eidx + E;

  char* p = (char*)d_ws;
  auto alloc = [&](size_t bytes) -> char* { char* r = p; p += WS_ALIGN(bytes); return r; };
  int*   deg    = (int*)  alloc(sizeof(int) * N);
  float* dis    = (float*)alloc(sizeof(float) * N);
  int*   rowptr = (int*)  alloc(sizeof(int) * (N + 1));
  int*   cursor = (int*)  alloc(sizeof(int) * N);
  unsigned short* csr16 = (unsigned short*)alloc(sizeof(unsigned short) * (size_t)E);
  unsigned int*   packed = (unsigned int*) alloc(sizeof(unsigned int) * (size_t)E);
  float* bufA   = (float*)alloc(sizeof(float) * (size_t)N * HID);  // h1s / h2s; reused as decode partials
  float* bufB   = (float*)alloc(sizeof(float) * (size_t)N * HID);  // z1 (row-major) / z2 (slice-major)

  const int T = 256;
  const int PG = 2048;  // persistent grid: 8 blocks/CU, 256 blocks/XCD

  hipMemsetAsync(deg, 0, sizeof(int) * N, stream);
  hipLaunchKernelGGL(k_pack_count, dim3((E + T - 1) / T), dim3(T), 0, stream,
                     esrc, edst, E, packed, deg);
  hipLaunchKernelGGL(k_dis, dim3((N + T - 1) / T), dim3(T), 0, stream, deg, dis, N);
  hipLaunchKernelGGL(k_scan, dim3(1), dim3(1024), 0, stream, deg, rowptr, cursor, N, E);
  hipLaunchKernelGGL(k_fill_xcd, dim3(PG), dim3(T), 0, stream, packed, E, N, cursor, csr16);

  // conv1: h1s = (x @ W1)*dis[row] slice-major (MFMA split-bf16); z1 row-major
  dim3 g1((N + 127) / 128, HID / 64);
  hipLaunchKernelGGL(k_gemm_mfma_sm, g1, dim3(256), 0, stream, x, W1, dis, bufA, N, HID, IN_CH);
  hipLaunchKernelGGL((k_agg_xcd<256, false>), dim3(PG), dim3(256), 0, stream,
                     bufA, rowptr, csr16, dis, b1, bufB, N, 1, 0);
  hipLaunchKernelGGL((k_agg_xcd<256, false>), dim3(PG), dim3(256), 0, stream,
                     bufA, rowptr, csr16, dis, b1, bufB, N, 1, 1);

  // conv2: h2s = (z1 @ W2)*dis[row] slice-major; z2 slice-major
  dim3 g2((N + 127) / 128, OUT_CH / 64);
  hipLaunchKernelGGL(k_gemm_mfma_sm, g2, dim3(256), 0, stream, bufB, W2, dis, bufA, N, OUT_CH, HID);
  hipLaunchKernelGGL((k_agg_xcd<128, true>), dim3(PG), dim3(256), 0, stream,
                     bufA, rowptr, csr16, dis, b2, bufB, N, 0, 0);

  // decode: per-XCD slice partial dots into bufA (h2s dead), then reduce
  hipLaunchKernelGGL(k_decode_xcd4, dim3(PG), dim3(256), 0, stream,
                     bufB, packed, bufA, E, N);
  hipLaunchKernelGGL(k_dreduce4, dim3((E / 4 + 255) / 256), dim3(256), 0, stream,
                     bufA, out, E);
}